// Round 9
// baseline (205.802 us; speedup 1.0000x reference)
//
#include <hip/hip_runtime.h>
#include <math.h>

#define TT 128
#define BB 4
#define NT (BB*TT*TT)                 // 65536 elements per [B,T,T]
#define N4 ((size_t)BB*TT*TT*TT)      // 8388608 elements per [B,T,T,T]
#define TEN3(b,x,y) (((b)*TT + (x))*TT + (y))

typedef _Float16 h4v __attribute__((ext_vector_type(4)));
typedef float    f4v __attribute__((ext_vector_type(4)));

__device__ __forceinline__ float sigm(float x) { return 1.0f / (1.0f + __expf(-x)); }
__device__ __forceinline__ float4 ld4(const float* __restrict__ p) {
    return *reinterpret_cast<const float4*>(p);
}
__device__ __forceinline__ f4v ldv4(const float* __restrict__ p) {
    return *reinterpret_cast<const f4v*>(p);
}
__device__ __forceinline__ float4 fma4s(const float s, const float4 v, const float4 acc) {
    return make_float4(fmaf(s, v.x, acc.x), fmaf(s, v.y, acc.y),
                       fmaf(s, v.z, acc.z), fmaf(s, v.w, acc.w));
}
__device__ __forceinline__ float4 fma4v(const float4 s, const float4 v, const float4 acc) {
    return make_float4(fmaf(s.x, v.x, acc.x), fmaf(s.y, v.y, acc.y),
                       fmaf(s.z, v.z, acc.z), fmaf(s.w, v.w, acc.w));
}
__device__ __forceinline__ float dot4(const float4 a, const float4 b) {
    return a.x*b.x + a.y*b.y + a.z*b.z + a.w*b.w;
}
__device__ __forceinline__ float4 cvt4(const h4v h) {
    return make_float4((float)h[0], (float)h[1], (float)h[2], (float)h[3]);
}
__device__ __forceinline__ h4v ldh4(const _Float16* __restrict__ p) {
    return *reinterpret_cast<const h4v*>(p);
}

__device__ __forceinline__ void prep_body(
    int chunk,
    const float* __restrict__ q_s, const float* __restrict__ q_h, const float* __restrict__ q_t,
    const float* __restrict__ span, const float* __restrict__ ph, const float* __restrict__ pt,
    float* __restrict__ sig_s, float* __restrict__ sig_h, float* __restrict__ sig_t,
    float* __restrict__ acc_s, float* __restrict__ acc_h, float* __restrict__ acc_t)
{
    const int idx = (chunk * 256 + threadIdx.x) * 4;
    f4v qs = ldv4(q_s + idx), qh = ldv4(q_h + idx), qt = ldv4(q_t + idx);
    f4v sp = ldv4(span + idx), hh = ldv4(ph + idx), tt = ldv4(pt + idx);
    f4v os, oh, ot;
    #pragma unroll
    for (int e = 0; e < 4; ++e) {
        os[e] = sigm(qs[e]); oh[e] = sigm(qh[e]); ot[e] = sigm(qt[e]);
    }
    *reinterpret_cast<f4v*>(sig_s + idx) = os;
    *reinterpret_cast<f4v*>(sig_h + idx) = oh;
    *reinterpret_cast<f4v*>(sig_t + idx) = ot;
    *reinterpret_cast<f4v*>(acc_s + idx) = sp;
    *reinterpret_cast<f4v*>(acc_h + idx) = hh;
    *reinterpret_cast<f4v*>(acc_t + idx) = tt;
}

// ---------------- one-shot: masked fp16 precompute + fused prep(t=0) ----------------
// 1D grid, XCD-aware: consecutive blockIdx round-robin across the 8 XCDs, so
// mapping group g = (bid&7)>>1 puts each mask group on exactly 2 XCDs -> each
// XCD's L2 sees only 3 read + 2 write streams (vs all 20), sequential within
// the XCD (chunk w = (bid>>3)*2 + (bid&1)). Per-block body identical to R6/R7:
// 4 chunks x 1024 elems, every load 64x16B contiguous, 12 loads in flight.
// bid >= 8192: fused prep for iteration 0 (independent of pm outputs).
__global__ __launch_bounds__(256) void pm_kernel(
    const float* __restrict__ rspan_psh, const float* __restrict__ rspan_pst, const float* __restrict__ m_r,
    const float* __restrict__ fspan_psh, const float* __restrict__ fspan_pst, const float* __restrict__ m_f,
    const float* __restrict__ ph_sib,    const float* __restrict__ pt_sib,    const float* __restrict__ m_sb,
    const float* __restrict__ ph_cop,    const float* __restrict__ pt_cop,    const float* __restrict__ m_cp,
    _Float16* __restrict__ t_r1, _Float16* __restrict__ t_r2,
    _Float16* __restrict__ t_f3, _Float16* __restrict__ t_f4,
    _Float16* __restrict__ t_s6, _Float16* __restrict__ t_s9,
    _Float16* __restrict__ t_c7, _Float16* __restrict__ t_c11,
    const float* __restrict__ span, const float* __restrict__ ph, const float* __restrict__ pt,
    float* __restrict__ sig_s, float* __restrict__ sig_h, float* __restrict__ sig_t,
    float* __restrict__ acc_s, float* __restrict__ acc_h, float* __restrict__ acc_t)
{
    const unsigned bid = blockIdx.x;
    if (bid >= 8192) {
        prep_body(bid - 8192, span, ph, pt, span, ph, pt,
                  sig_s, sig_h, sig_t, acc_s, acc_h, acc_t);
        return;
    }
    const unsigned g = (bid & 7u) >> 1;                    // group -> XCD pair
    const unsigned w = ((bid >> 3) << 1) | (bid & 1u);     // chunk within group [0,2048)

    const float *va, *vb, *mk;
    _Float16 *oa, *ob;
    switch (g) {
        case 0:  va = rspan_psh; vb = rspan_pst; mk = m_r;  oa = t_r1; ob = t_r2;  break;
        case 1:  va = fspan_psh; vb = fspan_pst; mk = m_f;  oa = t_f3; ob = t_f4;  break;
        case 2:  va = ph_sib;    vb = pt_sib;    mk = m_sb; oa = t_s6; ob = t_s9;  break;
        default: va = ph_cop;    vb = pt_cop;    mk = m_cp; oa = t_c7; ob = t_c11; break;
    }
    const size_t base = (size_t)w * 4096 + (size_t)threadIdx.x * 4;

    f4v m[4], a[4], b[4];
    #pragma unroll
    for (int c = 0; c < 4; ++c) m[c] = ldv4(mk + base + c * 1024);
    #pragma unroll
    for (int c = 0; c < 4; ++c) a[c] = ldv4(va + base + c * 1024);
    #pragma unroll
    for (int c = 0; c < 4; ++c) b[c] = ldv4(vb + base + c * 1024);

    #pragma unroll
    for (int c = 0; c < 4; ++c) {
        h4v ha, hb;
        #pragma unroll
        for (int e = 0; e < 4; ++e) {
            ha[e] = (_Float16)(a[c][e] * m[c][e]);
            hb[e] = (_Float16)(b[c][e] * m[c][e]);
        }
        *reinterpret_cast<h4v*>(oa + base + c * 1024) = ha;
        *reinterpret_cast<h4v*>(ob + base + c * 1024) = hb;
    }
}

// ---------------- per-iteration prep (iterations 1,2) ----------------
__global__ __launch_bounds__(256) void prep_kernel(
    const float* __restrict__ q_s, const float* __restrict__ q_h, const float* __restrict__ q_t,
    const float* __restrict__ span, const float* __restrict__ ph, const float* __restrict__ pt,
    float* __restrict__ sig_s, float* __restrict__ sig_h, float* __restrict__ sig_t,
    float* __restrict__ acc_s, float* __restrict__ acc_h, float* __restrict__ acc_t)
{
    prep_body(blockIdx.x, q_s, q_h, q_t, span, ph, pt,
              sig_s, sig_h, sig_t, acc_s, acc_h, acc_t);
}

// ---------------- fused iteration kernel ----------------
// blockIdx.z in [0,BB): K1 role (block fixed (b,j), loops i)
// blockIdx.z in [BB,2BB): K2 role (block fixed (b,i), loops j)
// All acc updates are atomicAdd (never read) -> role interleaving is race-free.
__global__ __launch_bounds__(256) void iter_kernel(
    const _Float16* __restrict__ t_r1, const _Float16* __restrict__ t_r2,
    const _Float16* __restrict__ t_f4,
    const _Float16* __restrict__ t_f3, const _Float16* __restrict__ t_s6,
    const _Float16* __restrict__ t_s9, const _Float16* __restrict__ t_c7,
    const _Float16* __restrict__ t_c11,
    const float* __restrict__ sig_s, const float* __restrict__ sig_h, const float* __restrict__ sig_t,
    float* __restrict__ acc_s, float* __restrict__ acc_h, float* __restrict__ acc_t)
{
    __shared__ float s_red[2][8][128];
    const int sub = threadIdx.x >> 5;
    const int kq  = threadIdx.x & 31;
    const int k4  = kq << 2;

    if (blockIdx.z < BB) {
        // ---- K1 role ----
        const int j = blockIdx.y, b = blockIdx.z;
        const int i0 = blockIdx.x * 16;

        const float4 ss_jk = ld4(&sig_s[TEN3(b, j, k4)]);
        const float4 st_jk = ld4(&sig_t[TEN3(b, j, k4)]);

        float4 accspan = make_float4(0.f,0.f,0.f,0.f);
        float4 accpt   = make_float4(0.f,0.f,0.f,0.f);
        float red5[2], red4[2];

        const size_t base = (size_t)b * TT * TT * TT + (size_t)j * TT + k4;

        #pragma unroll
        for (int step = 0; step < 2; ++step) {
            const int i = i0 + step * 8 + sub;
            const size_t rb = base + (size_t)i * (TT * TT);

            const float4 v1 = cvt4(ldh4(t_r1 + rb));
            const float4 v2 = cvt4(ldh4(t_r2 + rb));
            const float4 v4 = cvt4(ldh4(t_f4 + rb));

            const float  sh_ij = sig_h[TEN3(b, i, j)];
            const float  ss_ij = sig_s[TEN3(b, i, j)];
            const float4 st_ik = ld4(&sig_t[TEN3(b, i, k4)]);

            accspan = fma4s(sh_ij, v1, accspan);   // (1)
            accspan = fma4v(st_ik, v2, accspan);   // (2)
            accpt   = fma4s(ss_ij, v4, accpt);     // (12)
            red5[step] = dot4(ss_jk, v1);          // (5)
            red4[step] = dot4(st_jk, v4);          // (4)
        }

        #pragma unroll
        for (int off = 16; off; off >>= 1) {
            #pragma unroll
            for (int s2 = 0; s2 < 2; ++s2) {
                red5[s2] += __shfl_xor(red5[s2], off, 64);
                red4[s2] += __shfl_xor(red4[s2], off, 64);
            }
        }
        if (kq == 0) {
            #pragma unroll
            for (int s2 = 0; s2 < 2; ++s2) {
                const int i = i0 + s2 * 8 + sub;
                atomicAdd(&acc_h[TEN3(b, i, j)], red5[s2]);
                atomicAdd(&acc_s[TEN3(b, i, j)], red4[s2]);
            }
        }

        *reinterpret_cast<float4*>(&s_red[0][sub][k4]) = accspan;
        *reinterpret_cast<float4*>(&s_red[1][sub][k4]) = accpt;
        __syncthreads();
        const int which = threadIdx.x >> 7;   // 0: span, 1: pt
        const int e     = threadIdx.x & 127;
        float s = 0.f;
        #pragma unroll
        for (int u = 0; u < 8; ++u) s += s_red[which][u][e];
        float* dst = which ? acc_t : acc_s;
        atomicAdd(&dst[TEN3(b, j, e)], s);
    } else {
        // ---- K2 role ----
        const int i = blockIdx.y, b = blockIdx.z - BB;
        const int j0 = blockIdx.x * 16;

        const float4 sh_ik = ld4(&sig_h[TEN3(b, i, k4)]);
        const float4 st_ik = ld4(&sig_t[TEN3(b, i, k4)]);

        float4 accph = make_float4(0.f,0.f,0.f,0.f);
        float4 accpt = make_float4(0.f,0.f,0.f,0.f);
        float red3[2], red6[2], red9[2];

        const size_t base = (size_t)b * TT * TT * TT + (size_t)i * (TT * TT) + k4;

        #pragma unroll
        for (int step = 0; step < 2; ++step) {
            const int j = j0 + step * 8 + sub;
            const size_t rb = base + (size_t)j * TT;

            const float4 v3  = cvt4(ldh4(t_f3  + rb));
            const float4 v6  = cvt4(ldh4(t_s6  + rb));
            const float4 v9  = cvt4(ldh4(t_s9  + rb));
            const float4 v7  = cvt4(ldh4(t_c7  + rb));
            const float4 v11 = cvt4(ldh4(t_c11 + rb));
            const float4 v10 = cvt4(ldh4(t_r2  + rb));

            const float  ss_ij = sig_s[TEN3(b, i, j)];
            const float4 sh_jk = ld4(&sig_h[TEN3(b, j, k4)]);
            const float4 st_jk = ld4(&sig_t[TEN3(b, j, k4)]);
            const float4 ss_jk = ld4(&sig_s[TEN3(b, j, k4)]);

            accph = fma4s(ss_ij, v3,  accph);   // (8)
            accph = fma4v(sh_jk, v7,  accph);   // (7)
            accpt = fma4v(st_jk, v11, accpt);   // (11)
            accpt = fma4v(ss_jk, v10, accpt);   // (10)

            red3[step] = dot4(sh_ik, v3);       // (3)
            red6[step] = dot4(sh_ik, v6);       // (6)
            red9[step] = dot4(st_ik, v9);       // (9)
        }

        #pragma unroll
        for (int off = 16; off; off >>= 1) {
            #pragma unroll
            for (int s2 = 0; s2 < 2; ++s2) {
                red3[s2] += __shfl_xor(red3[s2], off, 64);
                red6[s2] += __shfl_xor(red6[s2], off, 64);
                red9[s2] += __shfl_xor(red9[s2], off, 64);
            }
        }
        if (kq == 0) {
            #pragma unroll
            for (int s2 = 0; s2 < 2; ++s2) {
                const int j = j0 + s2 * 8 + sub;
                atomicAdd(&acc_s[TEN3(b, i, j)], red3[s2]);
                atomicAdd(&acc_h[TEN3(b, i, j)], red6[s2]);
                atomicAdd(&acc_t[TEN3(b, i, j)], red9[s2]);
            }
        }

        *reinterpret_cast<float4*>(&s_red[0][sub][k4]) = accph;
        *reinterpret_cast<float4*>(&s_red[1][sub][k4]) = accpt;
        __syncthreads();
        const int which = threadIdx.x >> 7;   // 0: ph, 1: pt
        const int e     = threadIdx.x & 127;
        float s = 0.f;
        #pragma unroll
        for (int u = 0; u < 8; ++u) s += s_red[which][u][e];
        float* dst = which ? acc_t : acc_h;
        atomicAdd(&dst[TEN3(b, i, e)], s);
    }
}

extern "C" void kernel_launch(void* const* d_in, const int* in_sizes, int n_in,
                              void* d_out, int out_size, void* d_ws, size_t ws_size,
                              hipStream_t stream)
{
    const float* span      = (const float*)d_in[0];
    const float* ph        = (const float*)d_in[1];
    const float* pt        = (const float*)d_in[2];
    const float* rspan_psh = (const float*)d_in[3];
    const float* rspan_pst = (const float*)d_in[4];
    const float* fspan_psh = (const float*)d_in[5];
    const float* fspan_pst = (const float*)d_in[6];
    const float* ph_sib    = (const float*)d_in[7];
    const float* pt_sib    = (const float*)d_in[8];
    const float* ph_cop    = (const float*)d_in[9];
    const float* pt_cop    = (const float*)d_in[10];
    const float* m_p2rspan = (const float*)d_in[11];
    const float* m_psib    = (const float*)d_in[12];
    const float* m_pcop    = (const float*)d_in[13];
    const float* m_pspan2r = (const float*)d_in[14];

    float* ws = (float*)d_ws;
    float* sig_s = ws + 0 * NT;
    float* sig_h = ws + 1 * NT;
    float* sig_t = ws + 2 * NT;
    float* A_s   = ws + 3 * NT;
    float* A_h   = ws + 4 * NT;
    float* A_t   = ws + 5 * NT;
    float* B_s   = ws + 6 * NT;
    float* B_h   = ws + 7 * NT;
    float* B_t   = ws + 8 * NT;
    float* O_s   = (float*)d_out;
    float* O_h   = O_s + NT;
    float* O_t   = O_s + 2 * NT;

    _Float16* hbase = (_Float16*)(ws + 9 * NT);
    _Float16* t_r1  = hbase + 0 * N4;
    _Float16* t_r2  = hbase + 1 * N4;
    _Float16* t_f4  = hbase + 2 * N4;
    _Float16* t_f3  = hbase + 3 * N4;
    _Float16* t_s6  = hbase + 4 * N4;
    _Float16* t_s9  = hbase + 5 * N4;
    _Float16* t_c7  = hbase + 6 * N4;
    _Float16* t_c11 = hbase + 7 * N4;

    struct Iter { const float *qs, *qh, *qt; float *as, *ah, *at; };
    const Iter it[3] = {
        { span, ph, pt,  A_s, A_h, A_t },
        { A_s, A_h, A_t, B_s, B_h, B_t },
        { B_s, B_h, B_t, O_s, O_h, O_t },
    };

    // pm (masked fp16 precompute, XCD-aware 1D grid) + fused prep(t=0):
    // 8192 pm blocks + 64 prep blocks.
    pm_kernel<<<8256, 256, 0, stream>>>(
        rspan_psh, rspan_pst, m_p2rspan,
        fspan_psh, fspan_pst, m_pspan2r,
        ph_sib, pt_sib, m_psib,
        ph_cop, pt_cop, m_pcop,
        t_r1, t_r2, t_f3, t_f4, t_s6, t_s9, t_c7, t_c11,
        span, ph, pt,
        sig_s, sig_h, sig_t, A_s, A_h, A_t);

    const dim3 gridI(8, TT, 2 * BB);   // 8192 blocks: K1 roles z<4, K2 roles z>=4
    const dim3 blk(256);

    for (int t = 0; t < 3; ++t) {
        if (t > 0) {
            prep_kernel<<<NT / 1024, 256, 0, stream>>>(
                it[t].qs, it[t].qh, it[t].qt, span, ph, pt,
                sig_s, sig_h, sig_t, it[t].as, it[t].ah, it[t].at);
        }
        iter_kernel<<<gridI, blk, 0, stream>>>(
            t_r1, t_r2, t_f4, t_f3, t_s6, t_s9, t_c7, t_c11,
            sig_s, sig_h, sig_t, it[t].as, it[t].ah, it[t].at);
    }
}

// Round 10
// 195.799 us; speedup vs baseline: 1.0511x; 1.0511x over previous
//
#include <hip/hip_runtime.h>
#include <math.h>

#define TT 128
#define BB 4
#define NT (BB*TT*TT)                 // 65536 elements per [B,T,T]
#define N4 ((size_t)BB*TT*TT*TT)      // 8388608 elements per [B,T,T,T]
#define TEN3(b,x,y) (((b)*TT + (x))*TT + (y))

typedef _Float16 h4v __attribute__((ext_vector_type(4)));
typedef float    f4v __attribute__((ext_vector_type(4)));

__device__ __forceinline__ float sigm(float x) { return 1.0f / (1.0f + __expf(-x)); }
__device__ __forceinline__ float4 ld4(const float* __restrict__ p) {
    return *reinterpret_cast<const float4*>(p);
}
__device__ __forceinline__ f4v ldv4(const float* __restrict__ p) {
    return *reinterpret_cast<const f4v*>(p);
}
__device__ __forceinline__ float4 fma4s(const float s, const float4 v, const float4 acc) {
    return make_float4(fmaf(s, v.x, acc.x), fmaf(s, v.y, acc.y),
                       fmaf(s, v.z, acc.z), fmaf(s, v.w, acc.w));
}
__device__ __forceinline__ float4 fma4v(const float4 s, const float4 v, const float4 acc) {
    return make_float4(fmaf(s.x, v.x, acc.x), fmaf(s.y, v.y, acc.y),
                       fmaf(s.z, v.z, acc.z), fmaf(s.w, v.w, acc.w));
}
__device__ __forceinline__ float dot4(const float4 a, const float4 b) {
    return a.x*b.x + a.y*b.y + a.z*b.z + a.w*b.w;
}
__device__ __forceinline__ float4 cvt4(const h4v h) {
    return make_float4((float)h[0], (float)h[1], (float)h[2], (float)h[3]);
}
__device__ __forceinline__ h4v ldh4(const _Float16* __restrict__ p) {
    return *reinterpret_cast<const h4v*>(p);
}

__device__ __forceinline__ void prep_body(
    int chunk,
    const float* __restrict__ q_s, const float* __restrict__ q_h, const float* __restrict__ q_t,
    const float* __restrict__ span, const float* __restrict__ ph, const float* __restrict__ pt,
    float* __restrict__ sig_s, float* __restrict__ sig_h, float* __restrict__ sig_t,
    float* __restrict__ acc_s, float* __restrict__ acc_h, float* __restrict__ acc_t)
{
    const int idx = (chunk * 256 + threadIdx.x) * 4;
    f4v qs = ldv4(q_s + idx), qh = ldv4(q_h + idx), qt = ldv4(q_t + idx);
    f4v sp = ldv4(span + idx), hh = ldv4(ph + idx), tt = ldv4(pt + idx);
    f4v os, oh, ot;
    #pragma unroll
    for (int e = 0; e < 4; ++e) {
        os[e] = sigm(qs[e]); oh[e] = sigm(qh[e]); ot[e] = sigm(qt[e]);
    }
    *reinterpret_cast<f4v*>(sig_s + idx) = os;
    *reinterpret_cast<f4v*>(sig_h + idx) = oh;
    *reinterpret_cast<f4v*>(sig_t + idx) = ot;
    *reinterpret_cast<f4v*>(acc_s + idx) = sp;
    *reinterpret_cast<f4v*>(acc_h + idx) = hh;
    *reinterpret_cast<f4v*>(acc_t + idx) = tt;
}

// ---------------- one-shot: masked fp16 precompute + fused prep(t=0) ----------------
// y selects mask group; x<2048: pm chunked coalesced (R5/R6-proven ~135us body).
// y==0, x in [2048,2112): prep for iteration 0 (independent of pm outputs).
__global__ __launch_bounds__(256) void pm_kernel(
    const float* __restrict__ rspan_psh, const float* __restrict__ rspan_pst, const float* __restrict__ m_r,
    const float* __restrict__ fspan_psh, const float* __restrict__ fspan_pst, const float* __restrict__ m_f,
    const float* __restrict__ ph_sib,    const float* __restrict__ pt_sib,    const float* __restrict__ m_sb,
    const float* __restrict__ ph_cop,    const float* __restrict__ pt_cop,    const float* __restrict__ m_cp,
    _Float16* __restrict__ t_r1, _Float16* __restrict__ t_r2,
    _Float16* __restrict__ t_f3, _Float16* __restrict__ t_f4,
    _Float16* __restrict__ t_s6, _Float16* __restrict__ t_s9,
    _Float16* __restrict__ t_c7, _Float16* __restrict__ t_c11,
    const float* __restrict__ span, const float* __restrict__ ph, const float* __restrict__ pt,
    float* __restrict__ sig_s, float* __restrict__ sig_h, float* __restrict__ sig_t,
    float* __restrict__ acc_s, float* __restrict__ acc_h, float* __restrict__ acc_t)
{
    if (blockIdx.x >= 2048) {
        if (blockIdx.y == 0) {
            prep_body(blockIdx.x - 2048, span, ph, pt, span, ph, pt,
                      sig_s, sig_h, sig_t, acc_s, acc_h, acc_t);
        }
        return;
    }
    const float *va, *vb, *mk;
    _Float16 *oa, *ob;
    switch (blockIdx.y) {
        case 0:  va = rspan_psh; vb = rspan_pst; mk = m_r;  oa = t_r1; ob = t_r2;  break;
        case 1:  va = fspan_psh; vb = fspan_pst; mk = m_f;  oa = t_f3; ob = t_f4;  break;
        case 2:  va = ph_sib;    vb = pt_sib;    mk = m_sb; oa = t_s6; ob = t_s9;  break;
        default: va = ph_cop;    vb = pt_cop;    mk = m_cp; oa = t_c7; ob = t_c11; break;
    }
    const size_t base = (size_t)blockIdx.x * 4096 + (size_t)threadIdx.x * 4;

    f4v m[4], a[4], b[4];
    #pragma unroll
    for (int c = 0; c < 4; ++c) m[c] = ldv4(mk + base + c * 1024);
    #pragma unroll
    for (int c = 0; c < 4; ++c) a[c] = ldv4(va + base + c * 1024);
    #pragma unroll
    for (int c = 0; c < 4; ++c) b[c] = ldv4(vb + base + c * 1024);

    #pragma unroll
    for (int c = 0; c < 4; ++c) {
        h4v ha, hb;
        #pragma unroll
        for (int e = 0; e < 4; ++e) {
            ha[e] = (_Float16)(a[c][e] * m[c][e]);
            hb[e] = (_Float16)(b[c][e] * m[c][e]);
        }
        *reinterpret_cast<h4v*>(oa + base + c * 1024) = ha;
        *reinterpret_cast<h4v*>(ob + base + c * 1024) = hb;
    }
}

// ---------------- per-iteration prep (iterations 1,2) ----------------
__global__ __launch_bounds__(256) void prep_kernel(
    const float* __restrict__ q_s, const float* __restrict__ q_h, const float* __restrict__ q_t,
    const float* __restrict__ span, const float* __restrict__ ph, const float* __restrict__ pt,
    float* __restrict__ sig_s, float* __restrict__ sig_h, float* __restrict__ sig_t,
    float* __restrict__ acc_s, float* __restrict__ acc_h, float* __restrict__ acc_t)
{
    prep_body(blockIdx.x, q_s, q_h, q_t, span, ph, pt,
              sig_s, sig_h, sig_t, acc_s, acc_h, acc_t);
}

// ---------------- fused iteration kernel ----------------
// blockIdx.z in [0,BB): K1 role (block fixed (b,j), loops i)
// blockIdx.z in [BB,2BB): K2 role (block fixed (b,i), loops j)
// All acc updates are atomicAdd (never read) -> role interleaving is race-free.
__global__ __launch_bounds__(256) void iter_kernel(
    const _Float16* __restrict__ t_r1, const _Float16* __restrict__ t_r2,
    const _Float16* __restrict__ t_f4,
    const _Float16* __restrict__ t_f3, const _Float16* __restrict__ t_s6,
    const _Float16* __restrict__ t_s9, const _Float16* __restrict__ t_c7,
    const _Float16* __restrict__ t_c11,
    const float* __restrict__ sig_s, const float* __restrict__ sig_h, const float* __restrict__ sig_t,
    float* __restrict__ acc_s, float* __restrict__ acc_h, float* __restrict__ acc_t)
{
    __shared__ float s_red[2][8][128];
    const int sub = threadIdx.x >> 5;
    const int kq  = threadIdx.x & 31;
    const int k4  = kq << 2;

    if (blockIdx.z < BB) {
        // ---- K1 role ----
        const int j = blockIdx.y, b = blockIdx.z;
        const int i0 = blockIdx.x * 16;

        const float4 ss_jk = ld4(&sig_s[TEN3(b, j, k4)]);
        const float4 st_jk = ld4(&sig_t[TEN3(b, j, k4)]);

        float4 accspan = make_float4(0.f,0.f,0.f,0.f);
        float4 accpt   = make_float4(0.f,0.f,0.f,0.f);
        float red5[2], red4[2];

        const size_t base = (size_t)b * TT * TT * TT + (size_t)j * TT + k4;

        #pragma unroll
        for (int step = 0; step < 2; ++step) {
            const int i = i0 + step * 8 + sub;
            const size_t rb = base + (size_t)i * (TT * TT);

            const float4 v1 = cvt4(ldh4(t_r1 + rb));
            const float4 v2 = cvt4(ldh4(t_r2 + rb));
            const float4 v4 = cvt4(ldh4(t_f4 + rb));

            const float  sh_ij = sig_h[TEN3(b, i, j)];
            const float  ss_ij = sig_s[TEN3(b, i, j)];
            const float4 st_ik = ld4(&sig_t[TEN3(b, i, k4)]);

            accspan = fma4s(sh_ij, v1, accspan);   // (1)
            accspan = fma4v(st_ik, v2, accspan);   // (2)
            accpt   = fma4s(ss_ij, v4, accpt);     // (12)
            red5[step] = dot4(ss_jk, v1);          // (5)
            red4[step] = dot4(st_jk, v4);          // (4)
        }

        #pragma unroll
        for (int off = 16; off; off >>= 1) {
            #pragma unroll
            for (int s2 = 0; s2 < 2; ++s2) {
                red5[s2] += __shfl_xor(red5[s2], off, 64);
                red4[s2] += __shfl_xor(red4[s2], off, 64);
            }
        }
        if (kq == 0) {
            #pragma unroll
            for (int s2 = 0; s2 < 2; ++s2) {
                const int i = i0 + s2 * 8 + sub;
                atomicAdd(&acc_h[TEN3(b, i, j)], red5[s2]);
                atomicAdd(&acc_s[TEN3(b, i, j)], red4[s2]);
            }
        }

        *reinterpret_cast<float4*>(&s_red[0][sub][k4]) = accspan;
        *reinterpret_cast<float4*>(&s_red[1][sub][k4]) = accpt;
        __syncthreads();
        const int which = threadIdx.x >> 7;   // 0: span, 1: pt
        const int e     = threadIdx.x & 127;
        float s = 0.f;
        #pragma unroll
        for (int u = 0; u < 8; ++u) s += s_red[which][u][e];
        float* dst = which ? acc_t : acc_s;
        atomicAdd(&dst[TEN3(b, j, e)], s);
    } else {
        // ---- K2 role ----
        const int i = blockIdx.y, b = blockIdx.z - BB;
        const int j0 = blockIdx.x * 16;

        const float4 sh_ik = ld4(&sig_h[TEN3(b, i, k4)]);
        const float4 st_ik = ld4(&sig_t[TEN3(b, i, k4)]);

        float4 accph = make_float4(0.f,0.f,0.f,0.f);
        float4 accpt = make_float4(0.f,0.f,0.f,0.f);
        float red3[2], red6[2], red9[2];

        const size_t base = (size_t)b * TT * TT * TT + (size_t)i * (TT * TT) + k4;

        #pragma unroll
        for (int step = 0; step < 2; ++step) {
            const int j = j0 + step * 8 + sub;
            const size_t rb = base + (size_t)j * TT;

            const float4 v3  = cvt4(ldh4(t_f3  + rb));
            const float4 v6  = cvt4(ldh4(t_s6  + rb));
            const float4 v9  = cvt4(ldh4(t_s9  + rb));
            const float4 v7  = cvt4(ldh4(t_c7  + rb));
            const float4 v11 = cvt4(ldh4(t_c11 + rb));
            const float4 v10 = cvt4(ldh4(t_r2  + rb));

            const float  ss_ij = sig_s[TEN3(b, i, j)];
            const float4 sh_jk = ld4(&sig_h[TEN3(b, j, k4)]);
            const float4 st_jk = ld4(&sig_t[TEN3(b, j, k4)]);
            const float4 ss_jk = ld4(&sig_s[TEN3(b, j, k4)]);

            accph = fma4s(ss_ij, v3,  accph);   // (8)
            accph = fma4v(sh_jk, v7,  accph);   // (7)
            accpt = fma4v(st_jk, v11, accpt);   // (11)
            accpt = fma4v(ss_jk, v10, accpt);   // (10)

            red3[step] = dot4(sh_ik, v3);       // (3)
            red6[step] = dot4(sh_ik, v6);       // (6)
            red9[step] = dot4(st_ik, v9);       // (9)
        }

        #pragma unroll
        for (int off = 16; off; off >>= 1) {
            #pragma unroll
            for (int s2 = 0; s2 < 2; ++s2) {
                red3[s2] += __shfl_xor(red3[s2], off, 64);
                red6[s2] += __shfl_xor(red6[s2], off, 64);
                red9[s2] += __shfl_xor(red9[s2], off, 64);
            }
        }
        if (kq == 0) {
            #pragma unroll
            for (int s2 = 0; s2 < 2; ++s2) {
                const int j = j0 + s2 * 8 + sub;
                atomicAdd(&acc_s[TEN3(b, i, j)], red3[s2]);
                atomicAdd(&acc_h[TEN3(b, i, j)], red6[s2]);
                atomicAdd(&acc_t[TEN3(b, i, j)], red9[s2]);
            }
        }

        *reinterpret_cast<float4*>(&s_red[0][sub][k4]) = accph;
        *reinterpret_cast<float4*>(&s_red[1][sub][k4]) = accpt;
        __syncthreads();
        const int which = threadIdx.x >> 7;   // 0: ph, 1: pt
        const int e     = threadIdx.x & 127;
        float s = 0.f;
        #pragma unroll
        for (int u = 0; u < 8; ++u) s += s_red[which][u][e];
        float* dst = which ? acc_t : acc_h;
        atomicAdd(&dst[TEN3(b, i, e)], s);
    }
}

extern "C" void kernel_launch(void* const* d_in, const int* in_sizes, int n_in,
                              void* d_out, int out_size, void* d_ws, size_t ws_size,
                              hipStream_t stream)
{
    const float* span      = (const float*)d_in[0];
    const float* ph        = (const float*)d_in[1];
    const float* pt        = (const float*)d_in[2];
    const float* rspan_psh = (const float*)d_in[3];
    const float* rspan_pst = (const float*)d_in[4];
    const float* fspan_psh = (const float*)d_in[5];
    const float* fspan_pst = (const float*)d_in[6];
    const float* ph_sib    = (const float*)d_in[7];
    const float* pt_sib    = (const float*)d_in[8];
    const float* ph_cop    = (const float*)d_in[9];
    const float* pt_cop    = (const float*)d_in[10];
    const float* m_p2rspan = (const float*)d_in[11];
    const float* m_psib    = (const float*)d_in[12];
    const float* m_pcop    = (const float*)d_in[13];
    const float* m_pspan2r = (const float*)d_in[14];

    float* ws = (float*)d_ws;
    float* sig_s = ws + 0 * NT;
    float* sig_h = ws + 1 * NT;
    float* sig_t = ws + 2 * NT;
    float* A_s   = ws + 3 * NT;
    float* A_h   = ws + 4 * NT;
    float* A_t   = ws + 5 * NT;
    float* B_s   = ws + 6 * NT;
    float* B_h   = ws + 7 * NT;
    float* B_t   = ws + 8 * NT;
    float* O_s   = (float*)d_out;
    float* O_h   = O_s + NT;
    float* O_t   = O_s + 2 * NT;

    _Float16* hbase = (_Float16*)(ws + 9 * NT);
    _Float16* t_r1  = hbase + 0 * N4;
    _Float16* t_r2  = hbase + 1 * N4;
    _Float16* t_f4  = hbase + 2 * N4;
    _Float16* t_f3  = hbase + 3 * N4;
    _Float16* t_s6  = hbase + 4 * N4;
    _Float16* t_s9  = hbase + 5 * N4;
    _Float16* t_c7  = hbase + 6 * N4;
    _Float16* t_c11 = hbase + 7 * N4;

    struct Iter { const float *qs, *qh, *qt; float *as, *ah, *at; };
    const Iter it[3] = {
        { span, ph, pt,  A_s, A_h, A_t },
        { A_s, A_h, A_t, B_s, B_h, B_t },
        { B_s, B_h, B_t, O_s, O_h, O_t },
    };

    // pm (masked fp16 precompute) + fused prep(t=0): grid (2048 pm + 64 prep, 4)
    const dim3 pm_grid(2112, 4);
    pm_kernel<<<pm_grid, 256, 0, stream>>>(
        rspan_psh, rspan_pst, m_p2rspan,
        fspan_psh, fspan_pst, m_pspan2r,
        ph_sib, pt_sib, m_psib,
        ph_cop, pt_cop, m_pcop,
        t_r1, t_r2, t_f3, t_f4, t_s6, t_s9, t_c7, t_c11,
        span, ph, pt,
        sig_s, sig_h, sig_t, A_s, A_h, A_t);

    const dim3 gridI(8, TT, 2 * BB);   // 8192 blocks: K1 roles z<4, K2 roles z>=4
    const dim3 blk(256);

    for (int t = 0; t < 3; ++t) {
        if (t > 0) {
            prep_kernel<<<NT / 1024, 256, 0, stream>>>(
                it[t].qs, it[t].qh, it[t].qt, span, ph, pt,
                sig_s, sig_h, sig_t, it[t].as, it[t].ah, it[t].at);
        }
        iter_kernel<<<gridI, blk, 0, stream>>>(
            t_r1, t_r2, t_f4, t_f3, t_s6, t_s9, t_c7, t_c11,
            sig_s, sig_h, sig_t, it[t].as, it[t].ah, it[t].at);
    }
}